// Round 6
// baseline (510.703 us; speedup 1.0000x reference)
//
#include <hip/hip_runtime.h>

#define NN 100000
#define NE 1600000
#define BK 128             // nodes per bucket
#define NBUK 782           // ceil(NN/128)
#define EB 8192            // edges per scatter block
#define NHB 98             // ceil(NE/16384) histogram blocks
#define NGRP 25000         // ceil(NN/4) node groups for sliced agg

typedef __attribute__((ext_vector_type(8))) short v8s;
typedef __attribute__((ext_vector_type(4))) float v4f;

__device__ __forceinline__ unsigned short f2bf(float f) {
  unsigned int u = __float_as_uint(f);
  unsigned int r = (u + 0x7FFFu + ((u >> 16) & 1u)) >> 16;
  return (unsigned short)r;
}
__device__ __forceinline__ float bflo(unsigned int w) { return __uint_as_float(w << 16); }
__device__ __forceinline__ float bfhi(unsigned int w) { return __uint_as_float(w & 0xFFFF0000u); }

// ---------------- per-block bucket histograms ----------------

__global__ __launch_bounds__(256) void k_hist(const int* __restrict__ dst,
                                              int* __restrict__ phist) {
  __shared__ int lh[NBUK];
  int t = threadIdx.x, b = blockIdx.x;
  for (int i = t; i < NBUK; i += 256) lh[i] = 0;
  __syncthreads();
  int base = b * 16384;
  int lim = min(16384, NE - base);
  for (int j = t; j < lim; j += 256) atomicAdd(&lh[dst[base + j] >> 7], 1);
  __syncthreads();
  for (int i = t; i < NBUK; i += 256) phist[b * NBUK + i] = lh[i];
}

// ---- reduce partials + exclusive scan -> hist,bbase,gcur; fused weight pack
__global__ __launch_bounds__(256) void k_scanb(const int* __restrict__ phist,
                                               int* __restrict__ hist,
                                               int* __restrict__ bbase,
                                               int* __restrict__ gcur,
                                               const float* __restrict__ W1l,
                                               const float* __restrict__ W1r,
                                               unsigned short* __restrict__ Wcat) {
  __shared__ int sc[256];
  __shared__ int carry;
  int t = threadIdx.x;
  for (int i = t; i < 32768; i += 256)
    Wcat[i] = f2bf((i < 16384) ? W1l[i] : W1r[i - 16384]);
  if (t == 0) carry = 0;
  __syncthreads();
  for (int c = 0; c < (NBUK + 255) / 256; ++c) {
    int i = c * 256 + t;
    int vv = 0;
    if (i < NBUK)
      for (int p = 0; p < NHB; ++p) vv += phist[p * NBUK + i];
    sc[t] = vv;
    __syncthreads();
    for (int o = 1; o < 256; o <<= 1) {
      int uu = (t >= o) ? sc[t - o] : 0;
      __syncthreads();
      sc[t] += uu;
      __syncthreads();
    }
    int excl = carry + sc[t] - vv;
    if (i < NBUK) { hist[i] = vv; bbase[i] = excl; gcur[i] = excl; }
    __syncthreads();
    if (t == 0) carry += sc[255];
    __syncthreads();
  }
}

// ---------------- LDS-staged bucket scatter (linear global writes) ---------
// staged[k] = (src<<7) | dstLocal, bucket-sorted.
__global__ __launch_bounds__(256) void k_scatter(const int* __restrict__ src,
                                                 const int* __restrict__ dst,
                                                 int* __restrict__ gcur,
                                                 unsigned int* __restrict__ staged) {
  __shared__ unsigned short stageI[EB];                 // 16 KB
  __shared__ int lhist[NBUK], lbase[NBUK], lcur[NBUK], gclaim[NBUK];  // 12.5 KB
  __shared__ int sc[256];
  __shared__ int carry;
  int t = threadIdx.x;
  int e0 = blockIdx.x * EB;
  int ecnt = min(EB, NE - e0);
  for (int i = t; i < NBUK; i += 256) lhist[i] = 0;
  if (t == 0) carry = 0;
  __syncthreads();
  for (int j = t; j < ecnt; j += 256) atomicAdd(&lhist[dst[e0 + j] >> 7], 1);
  __syncthreads();
  for (int c = 0; c < (NBUK + 255) / 256; ++c) {
    int i = c * 256 + t;
    int vv = (i < NBUK) ? lhist[i] : 0;
    sc[t] = vv;
    __syncthreads();
    for (int o = 1; o < 256; o <<= 1) {
      int uu = (t >= o) ? sc[t - o] : 0;
      __syncthreads();
      sc[t] += uu;
      __syncthreads();
    }
    int excl = carry + sc[t] - vv;
    if (i < NBUK) { lbase[i] = excl; lcur[i] = excl; }
    __syncthreads();
    if (t == 0) carry += sc[255];
    __syncthreads();
  }
  for (int b = t; b < NBUK; b += 256) {
    int c = lhist[b];
    gclaim[b] = c ? atomicAdd(&gcur[b], c) : 0;
  }
  __syncthreads();
  for (int j = t; j < ecnt; j += 256) {
    int b = dst[e0 + j] >> 7;
    int lp = atomicAdd(&lcur[b], 1);
    stageI[lp] = (unsigned short)j;
  }
  __syncthreads();
  for (int i = t; i < ecnt; i += 256) {
    int j = stageI[i];
    int d = dst[e0 + j];
    int b = d >> 7;
    staged[gclaim[b] + (i - lbase[b])] =
        ((unsigned int)src[e0 + j] << 7) | (unsigned int)(d & 127);
  }
}

// ---------------- per-bucket radix pass 2: staged -> CSR + off + deg -------
__global__ __launch_bounds__(256) void k_sort2(const unsigned int* __restrict__ staged,
                                               const int* __restrict__ bbase,
                                               const int* __restrict__ hist,
                                               int* __restrict__ csr,
                                               int* __restrict__ off,
                                               int* __restrict__ deg) {
  __shared__ int h128[BK], c128[BK];
  __shared__ int wtot;
  int bkt = blockIdx.x, t = threadIdx.x;
  if (t < BK) h128[t] = 0;
  __syncthreads();
  int st = bbase[bkt], cnt = hist[bkt];
  for (int j = t; j < cnt; j += 256) atomicAdd(&h128[staged[st + j] & 127], 1);
  __syncthreads();
  int v = 0, inc = 0;
  if (t < BK) {
    v = h128[t];
    inc = v;
    for (int o = 1; o < 64; o <<= 1) {
      int uu = __shfl_up(inc, o, 64);
      if ((t & 63) >= o) inc += uu;
    }
    if (t == 63) wtot = inc;
  }
  __syncthreads();
  if (t < BK) {
    int excl = inc - v + ((t >= 64) ? wtot : 0);
    c128[t] = excl;
    int node = bkt * BK + t;
    if (node < NN) { off[node] = st + excl; deg[node] = v; }
  }
  __syncthreads();
  for (int j = t; j < cnt; j += 256) {
    unsigned pk = staged[st + j];
    int lp = atomicAdd(&c128[pk & 127], 1);
    csr[st + lp] = (int)(pk >> 7);
  }
}

// ---------------- MFMA GEMM: us = x@W1l^T, vs = x@W1r^T ----------
// outputs in slice-major layout [slice][node][16] bf16
__global__ __launch_bounds__(256) void k_gemm1(
    const float* __restrict__ x, const unsigned short* __restrict__ Wcat,
    unsigned short* __restrict__ us, unsigned short* __restrict__ vs) {
  int wave = threadIdx.x >> 6, l = threadIdx.x & 63;
  int m0 = blockIdx.x * 64 + wave * 16;
  if (m0 >= NN) return;
  int lr = l & 15, kq = l >> 4;
  int rowc = min(m0 + lr, NN - 1);

  v8s a[4];
#pragma unroll
  for (int ks = 0; ks < 4; ++ks) {
    const float* xp = x + (size_t)rowc * 128 + ks * 32 + kq * 8;
    float4 f0 = *(const float4*)xp;
    float4 f1 = *(const float4*)(xp + 4);
    v8s tv;
    tv[0] = (short)f2bf(f0.x); tv[1] = (short)f2bf(f0.y);
    tv[2] = (short)f2bf(f0.z); tv[3] = (short)f2bf(f0.w);
    tv[4] = (short)f2bf(f1.x); tv[5] = (short)f2bf(f1.y);
    tv[6] = (short)f2bf(f1.z); tv[7] = (short)f2bf(f1.w);
    a[ks] = tv;
  }

  v4f acc[16];
#pragma unroll
  for (int nt = 0; nt < 16; ++nt) acc[nt] = (v4f){0.f, 0.f, 0.f, 0.f};

#pragma unroll
  for (int nt = 0; nt < 16; ++nt) {
    const unsigned short* wrow = Wcat + (size_t)(nt * 16 + lr) * 128;
#pragma unroll
    for (int ks = 0; ks < 4; ++ks) {
      v8s b = *(const v8s*)(wrow + ks * 32 + kq * 8);
      acc[nt] = __builtin_amdgcn_mfma_f32_16x16x32_bf16(a[ks], b, acc[nt], 0, 0, 0);
    }
  }

#pragma unroll
  for (int nt = 0; nt < 16; ++nt) {
#pragma unroll
    for (int rr = 0; rr < 4; ++rr) {
      int mrow = m0 + kq * 4 + rr;
      if (mrow < NN) {
        unsigned short bv = f2bf(acc[nt][rr]);
        if (nt < 8) us[(size_t)nt * NN * 16 + (size_t)mrow * 16 + lr] = bv;
        else        vs[(size_t)(nt - 8) * NN * 16 + (size_t)mrow * 16 + lr] = bv;
      }
    }
  }
}

// ---------------- sliced mean-aggregation (XCD-L2-resident gather) ---------
// block handles 4 nodes x 1 slice; slice = blockIdx & 7 -> same XCD (mod-8
// round robin), so each XCD's gather working set is NN*32B = 3.2 MB < L2.
__global__ __launch_bounds__(256) void k_aggs(
    const unsigned short* __restrict__ us,
    const int* __restrict__ csr, const int* __restrict__ off,
    const int* __restrict__ deg,
    unsigned short* __restrict__ aggs) {
  int slice = blockIdx.x & 7;
  int node = (blockIdx.x >> 3) * 4 + (threadIdx.x >> 6);
  int l = threadIdx.x & 63;
  if (node >= NN) return;
  int eg = l >> 3, dp = l & 7;
  int cnt = deg[node], st = off[node];
  const unsigned int* ub = (const unsigned int*)us + (size_t)slice * NN * 8;

  float a0 = 0.f, a1 = 0.f;
  int e = eg;
  while (e + 8 < cnt) {
    int s0 = csr[st + e], s1 = csr[st + e + 8];
    unsigned int w0 = ub[(size_t)s0 * 8 + dp];
    unsigned int w1 = ub[(size_t)s1 * 8 + dp];
    a0 += bflo(w0) + bflo(w1);
    a1 += bfhi(w0) + bfhi(w1);
    e += 16;
  }
  if (e < cnt) {
    unsigned int w = ub[(size_t)csr[st + e] * 8 + dp];
    a0 += bflo(w); a1 += bfhi(w);
  }
#pragma unroll
  for (int m = 8; m < 64; m <<= 1) {
    a0 += __shfl_xor(a0, m, 64);
    a1 += __shfl_xor(a1, m, 64);
  }
  if (eg == 0) {
    float inv = 1.f / (float)max(cnt, 1);
    unsigned int pk = ((unsigned int)f2bf(a1 * inv) << 16) | f2bf(a0 * inv);
    ((unsigned int*)aggs)[(size_t)slice * NN * 8 + (size_t)node * 8 + dp] = pk;
  }
}

// ---------------- epilogue: h=relu(agg+v+b1); p=h@W2l^T, r=h@W2r^T ---------
__global__ __launch_bounds__(256) void k_post(
    const unsigned short* __restrict__ aggs, const unsigned short* __restrict__ vs,
    const float* __restrict__ b1,
    const float* __restrict__ W2l, const float* __restrict__ W2r,
    unsigned short* __restrict__ p16, float* __restrict__ r) {
  int node = blockIdx.x * 4 + (threadIdx.x >> 6);
  int l = threadIdx.x & 63;
  if (node >= NN) return;
  int sl = l >> 3, dp = l & 7;
  size_t idx = (size_t)sl * NN * 8 + (size_t)node * 8 + dp;
  unsigned int aw = ((const unsigned int*)aggs)[idx];
  unsigned int vw = ((const unsigned int*)vs)[idx];
  int dim = sl * 16 + dp * 2;
  float2 bb = *(const float2*)(b1 + dim);
  float h0 = fmaxf(bflo(aw) + bflo(vw) + bb.x, 0.f);
  float h1 = fmaxf(bfhi(aw) + bfhi(vw) + bb.y, 0.f);

#pragma unroll
  for (int o = 0; o < 8; ++o) {
    const float* wr = (o < 4) ? (W2l + o * 128) : (W2r + (o - 4) * 128);
    float2 wv = *(const float2*)(wr + dim);
    float s = h0 * wv.x + h1 * wv.y;
#pragma unroll
    for (int d = 32; d > 0; d >>= 1) s += __shfl_xor(s, d, 64);
    if (l == o) {
      if (o < 4) p16[(size_t)node * 4 + o] = f2bf(s);
      else       r[(size_t)node * 4 + (o - 4)] = s;
    }
  }
}

// ---------------- layer-2 aggregation (bf16 p, 8B rows) + final linear -----
__global__ void k_final(const unsigned short* __restrict__ p16,
                        const float* __restrict__ r,
                        const int* __restrict__ csr, const int* __restrict__ off,
                        const int* __restrict__ deg,
                        const float* __restrict__ b2,
                        const float* __restrict__ Wlin, const float* __restrict__ blin,
                        float* __restrict__ out) {
  int i = blockIdx.x * blockDim.x + threadIdx.x;
  if (i >= NN) return;
  int cnt = deg[i], st = off[i];
  const uint2* pr = (const uint2*)p16;
  float a0 = 0.f, a1 = 0.f, a2 = 0.f, a3 = 0.f;
  int e = 0;
  for (; e + 4 <= cnt; e += 4) {
    int s0 = csr[st + e], s1 = csr[st + e + 1], s2 = csr[st + e + 2], s3 = csr[st + e + 3];
    uint2 q0 = pr[s0], q1 = pr[s1], q2 = pr[s2], q3 = pr[s3];
    a0 += bflo(q0.x) + bflo(q1.x) + bflo(q2.x) + bflo(q3.x);
    a1 += bfhi(q0.x) + bfhi(q1.x) + bfhi(q2.x) + bfhi(q3.x);
    a2 += bflo(q0.y) + bflo(q1.y) + bflo(q2.y) + bflo(q3.y);
    a3 += bfhi(q0.y) + bfhi(q1.y) + bfhi(q2.y) + bfhi(q3.y);
  }
  for (; e < cnt; ++e) {
    uint2 q = pr[csr[st + e]];
    a0 += bflo(q.x); a1 += bfhi(q.x); a2 += bflo(q.y); a3 += bfhi(q.y);
  }
  float inv = 1.f / (float)max(cnt, 1);
  float4 rv = *(const float4*)(r + (size_t)i * 4);
  float g0 = a0 * inv + b2[0] + rv.x;
  float g1 = a1 * inv + b2[1] + rv.y;
  float g2 = a2 * inv + b2[2] + rv.z;
  float g3 = a3 * inv + b2[3] + rv.w;
  out[(size_t)i * 2 + 0] = g0 * Wlin[0] + g1 * Wlin[1] + g2 * Wlin[2] + g3 * Wlin[3] + blin[0];
  out[(size_t)i * 2 + 1] = g0 * Wlin[4] + g1 * Wlin[5] + g2 * Wlin[6] + g3 * Wlin[7] + blin[1];
}

// ---------------- launch ----------------

extern "C" void kernel_launch(void* const* d_in, const int* in_sizes, int n_in,
                              void* d_out, int out_size, void* d_ws, size_t ws_size,
                              hipStream_t stream) {
  const float* x    = (const float*)d_in[0];
  const int*   ei   = (const int*)d_in[1];
  const int*   src  = ei;
  const int*   dst  = ei + NE;
  const float* W1l  = (const float*)d_in[2];
  const float* b1   = (const float*)d_in[3];
  const float* W1r  = (const float*)d_in[4];
  const float* W2l  = (const float*)d_in[5];
  const float* b2   = (const float*)d_in[6];
  const float* W2r  = (const float*)d_in[7];
  const float* Wlin = (const float*)d_in[8];
  const float* blin = (const float*)d_in[9];
  float* out = (float*)d_out;

  char* w = (char*)d_ws;
  size_t o = 0;
  auto alloc = [&](size_t bytes) {
    void* pp = (void*)(w + o);
    o = (o + bytes + 255) & ~(size_t)255;
    return pp;
  };
  int* phist = (int*)alloc((size_t)NHB * NBUK * 4);
  int* hist  = (int*)alloc(NBUK * 4);
  int* bbase = (int*)alloc(NBUK * 4);
  int* gcur  = (int*)alloc(NBUK * 4);
  unsigned int* staged = (unsigned int*)alloc((size_t)NE * 4);
  int* csr   = (int*)alloc((size_t)NE * 4);
  int* offs  = (int*)alloc(NN * 4);
  int* deg   = (int*)alloc(NN * 4);
  unsigned short* Wcat = (unsigned short*)alloc(256 * 128 * 2);
  unsigned short* us   = (unsigned short*)alloc((size_t)NN * 128 * 2);
  unsigned short* vs   = (unsigned short*)alloc((size_t)NN * 128 * 2);
  unsigned short* aggs = (unsigned short*)alloc((size_t)NN * 128 * 2);
  unsigned short* p16  = (unsigned short*)alloc((size_t)NN * 4 * 2);
  float* rbuf = (float*)alloc((size_t)NN * 4 * 4);

  hipLaunchKernelGGL(k_hist,  dim3(NHB), dim3(256), 0, stream, dst, phist);
  hipLaunchKernelGGL(k_scanb, dim3(1), dim3(256), 0, stream,
                     phist, hist, bbase, gcur, W1l, W1r, Wcat);
  hipLaunchKernelGGL(k_scatter, dim3((NE + EB - 1) / EB), dim3(256), 0, stream,
                     src, dst, gcur, staged);
  hipLaunchKernelGGL(k_sort2, dim3(NBUK), dim3(256), 0, stream,
                     staged, bbase, hist, csr, offs, deg);
  hipLaunchKernelGGL(k_gemm1, dim3((NN + 63) / 64), dim3(256), 0, stream, x, Wcat, us, vs);
  hipLaunchKernelGGL(k_aggs,  dim3(NGRP * 8), dim3(256), 0, stream,
                     us, csr, offs, deg, aggs);
  hipLaunchKernelGGL(k_post,  dim3(NGRP), dim3(256), 0, stream,
                     aggs, vs, b1, W2l, W2r, p16, rbuf);
  hipLaunchKernelGGL(k_final, dim3((NN + 255) / 256), dim3(256), 0, stream,
                     p16, rbuf, csr, offs, deg, b2, Wlin, blin, out);
}

// Round 7
// 450.028 us; speedup vs baseline: 1.1348x; 1.1348x over previous
//
#include <hip/hip_runtime.h>

#define NN 100000
#define NE 1600000
#define BK 128             // nodes per bucket (scatter/sort)
#define NBUK 782           // ceil(NN/128)
#define EB 8192            // edges per scatter block
#define NHB 98             // ceil(NE/16384) histogram blocks
#define NGRP 25000         // ceil(NN/4) node groups (k_post)
#define NAGG 3125          // ceil(NN/32) node groups (k_aggs)

typedef __attribute__((ext_vector_type(8))) short v8s;
typedef __attribute__((ext_vector_type(4))) float v4f;

__device__ __forceinline__ unsigned short f2bf(float f) {
  unsigned int u = __float_as_uint(f);
  unsigned int r = (u + 0x7FFFu + ((u >> 16) & 1u)) >> 16;
  return (unsigned short)r;
}
__device__ __forceinline__ float bflo(unsigned int w) { return __uint_as_float(w << 16); }
__device__ __forceinline__ float bfhi(unsigned int w) { return __uint_as_float(w & 0xFFFF0000u); }

// ---------------- init: pack weights + zero hist ----------------

__global__ void k_init(const float* __restrict__ W1l, const float* __restrict__ W1r,
                       unsigned short* __restrict__ Wcat, int* __restrict__ hist) {
  int i = blockIdx.x * blockDim.x + threadIdx.x;  // 32768 threads
  Wcat[i] = f2bf((i < 16384) ? W1l[i] : W1r[i - 16384]);
  if (i < NBUK) hist[i] = 0;
}

// ---------------- bucket histogram (LDS partial + global atomic) ----------

__global__ __launch_bounds__(256) void k_hist(const int* __restrict__ dst,
                                              int* __restrict__ hist) {
  __shared__ int lh[NBUK];
  int t = threadIdx.x;
  for (int i = t; i < NBUK; i += 256) lh[i] = 0;
  __syncthreads();
  int base = blockIdx.x * 16384;
  int lim = min(16384, NE - base);
  for (int j = t; j < lim; j += 256) atomicAdd(&lh[dst[base + j] >> 7], 1);
  __syncthreads();
  for (int i = t; i < NBUK; i += 256) {
    int c = lh[i];
    if (c) atomicAdd(&hist[i], c);
  }
}

// ---------------- cheap exclusive scan over 782 buckets ----------------

__global__ __launch_bounds__(256) void k_scanb(const int* __restrict__ hist,
                                               int* __restrict__ bbase,
                                               int* __restrict__ gcur) {
  __shared__ int sc[256];
  __shared__ int carry;
  int t = threadIdx.x;
  if (t == 0) carry = 0;
  __syncthreads();
  for (int c = 0; c < (NBUK + 255) / 256; ++c) {
    int i = c * 256 + t;
    int vv = (i < NBUK) ? hist[i] : 0;
    sc[t] = vv;
    __syncthreads();
    for (int o = 1; o < 256; o <<= 1) {
      int uu = (t >= o) ? sc[t - o] : 0;
      __syncthreads();
      sc[t] += uu;
      __syncthreads();
    }
    int excl = carry + sc[t] - vv;
    if (i < NBUK) { bbase[i] = excl; gcur[i] = excl; }
    __syncthreads();
    if (t == 0) carry += sc[255];
    __syncthreads();
  }
}

// ---------------- LDS-staged bucket scatter (linear global writes) ---------

__global__ __launch_bounds__(256) void k_scatter(const int* __restrict__ src,
                                                 const int* __restrict__ dst,
                                                 int* __restrict__ gcur,
                                                 unsigned int* __restrict__ staged) {
  __shared__ unsigned short stageI[EB];                 // 16 KB
  __shared__ int lhist[NBUK], lbase[NBUK], lcur[NBUK], gclaim[NBUK];  // 12.5 KB
  __shared__ int sc[256];
  __shared__ int carry;
  int t = threadIdx.x;
  int e0 = blockIdx.x * EB;
  int ecnt = min(EB, NE - e0);
  for (int i = t; i < NBUK; i += 256) lhist[i] = 0;
  if (t == 0) carry = 0;
  __syncthreads();
  for (int j = t; j < ecnt; j += 256) atomicAdd(&lhist[dst[e0 + j] >> 7], 1);
  __syncthreads();
  for (int c = 0; c < (NBUK + 255) / 256; ++c) {
    int i = c * 256 + t;
    int vv = (i < NBUK) ? lhist[i] : 0;
    sc[t] = vv;
    __syncthreads();
    for (int o = 1; o < 256; o <<= 1) {
      int uu = (t >= o) ? sc[t - o] : 0;
      __syncthreads();
      sc[t] += uu;
      __syncthreads();
    }
    int excl = carry + sc[t] - vv;
    if (i < NBUK) { lbase[i] = excl; lcur[i] = excl; }
    __syncthreads();
    if (t == 0) carry += sc[255];
    __syncthreads();
  }
  for (int b = t; b < NBUK; b += 256) {
    int c = lhist[b];
    gclaim[b] = c ? atomicAdd(&gcur[b], c) : 0;
  }
  __syncthreads();
  for (int j = t; j < ecnt; j += 256) {
    int b = dst[e0 + j] >> 7;
    int lp = atomicAdd(&lcur[b], 1);
    stageI[lp] = (unsigned short)j;
  }
  __syncthreads();
  for (int i = t; i < ecnt; i += 256) {
    int j = stageI[i];
    int d = dst[e0 + j];
    int b = d >> 7;
    staged[gclaim[b] + (i - lbase[b])] =
        ((unsigned int)src[e0 + j] << 7) | (unsigned int)(d & 127);
  }
}

// ---------------- per-bucket radix pass 2: staged -> CSR + off + deg -------

__global__ __launch_bounds__(256) void k_sort2(const unsigned int* __restrict__ staged,
                                               const int* __restrict__ bbase,
                                               const int* __restrict__ hist,
                                               int* __restrict__ csr,
                                               int* __restrict__ off,
                                               int* __restrict__ deg) {
  __shared__ int h128[BK], c128[BK];
  __shared__ int wtot;
  int bkt = blockIdx.x, t = threadIdx.x;
  if (t < BK) h128[t] = 0;
  __syncthreads();
  int st = bbase[bkt], cnt = hist[bkt];
  for (int j = t; j < cnt; j += 256) atomicAdd(&h128[staged[st + j] & 127], 1);
  __syncthreads();
  int v = 0, inc = 0;
  if (t < BK) {
    v = h128[t];
    inc = v;
    for (int o = 1; o < 64; o <<= 1) {
      int uu = __shfl_up(inc, o, 64);
      if ((t & 63) >= o) inc += uu;
    }
    if (t == 63) wtot = inc;
  }
  __syncthreads();
  if (t < BK) {
    int excl = inc - v + ((t >= 64) ? wtot : 0);
    c128[t] = excl;
    int node = bkt * BK + t;
    if (node < NN) { off[node] = st + excl; deg[node] = v; }
  }
  __syncthreads();
  for (int j = t; j < cnt; j += 256) {
    unsigned pk = staged[st + j];
    int lp = atomicAdd(&c128[pk & 127], 1);
    csr[st + lp] = (int)(pk >> 7);
  }
}

// ---------------- MFMA GEMM: us = x@W1l^T, vs = x@W1r^T ----------
// outputs in slice-major layout [slice][node][16] bf16

__global__ __launch_bounds__(256) void k_gemm1(
    const float* __restrict__ x, const unsigned short* __restrict__ Wcat,
    unsigned short* __restrict__ us, unsigned short* __restrict__ vs) {
  int wave = threadIdx.x >> 6, l = threadIdx.x & 63;
  int m0 = blockIdx.x * 64 + wave * 16;
  if (m0 >= NN) return;
  int lr = l & 15, kq = l >> 4;
  int rowc = min(m0 + lr, NN - 1);

  v8s a[4];
#pragma unroll
  for (int ks = 0; ks < 4; ++ks) {
    const float* xp = x + (size_t)rowc * 128 + ks * 32 + kq * 8;
    float4 f0 = *(const float4*)xp;
    float4 f1 = *(const float4*)(xp + 4);
    v8s tv;
    tv[0] = (short)f2bf(f0.x); tv[1] = (short)f2bf(f0.y);
    tv[2] = (short)f2bf(f0.z); tv[3] = (short)f2bf(f0.w);
    tv[4] = (short)f2bf(f1.x); tv[5] = (short)f2bf(f1.y);
    tv[6] = (short)f2bf(f1.z); tv[7] = (short)f2bf(f1.w);
    a[ks] = tv;
  }

  v4f acc[16];
#pragma unroll
  for (int nt = 0; nt < 16; ++nt) acc[nt] = (v4f){0.f, 0.f, 0.f, 0.f};

#pragma unroll
  for (int nt = 0; nt < 16; ++nt) {
    const unsigned short* wrow = Wcat + (size_t)(nt * 16 + lr) * 128;
#pragma unroll
    for (int ks = 0; ks < 4; ++ks) {
      v8s b = *(const v8s*)(wrow + ks * 32 + kq * 8);
      acc[nt] = __builtin_amdgcn_mfma_f32_16x16x32_bf16(a[ks], b, acc[nt], 0, 0, 0);
    }
  }

#pragma unroll
  for (int nt = 0; nt < 16; ++nt) {
#pragma unroll
    for (int rr = 0; rr < 4; ++rr) {
      int mrow = m0 + kq * 4 + rr;
      if (mrow < NN) {
        unsigned short bv = f2bf(acc[nt][rr]);
        if (nt < 8) us[(size_t)nt * NN * 16 + (size_t)mrow * 16 + lr] = bv;
        else        vs[(size_t)(nt - 8) * NN * 16 + (size_t)mrow * 16 + lr] = bv;
      }
    }
  }
}

// ---------------- sliced mean-aggregation (XCD-L2-resident gather) ---------
// wave = 8 nodes x 8 dim-pairs; slice = blockIdx & 7 -> fixed XCD (mod-8
// round robin): per-XCD gather working set = NN*32B = 3.2 MB < 4 MiB L2.
// No cross-lane reduction: each lane accumulates its dim-pair directly.

__global__ __launch_bounds__(256) void k_aggs(
    const unsigned short* __restrict__ us,
    const int* __restrict__ csr, const int* __restrict__ off,
    const int* __restrict__ deg,
    unsigned short* __restrict__ aggs) {
  int slice = blockIdx.x & 7;
  int grp = blockIdx.x >> 3;               // 32 nodes per block
  int t = threadIdx.x;
  int wave = t >> 6, l = t & 63;
  int g = l >> 3, dp = l & 7;
  int node = grp * 32 + wave * 8 + g;
  const unsigned int* ub = (const unsigned int*)us + (size_t)slice * NN * 8;
  int cnt = 0, st = 0;
  if (node < NN) { cnt = deg[node]; st = off[node]; }

  float a0 = 0.f, a1 = 0.f;
  int s = (cnt > 0) ? csr[st] : 0;
  for (int e = 0; e < cnt; ++e) {
    int sn = (e + 1 < cnt) ? csr[st + e + 1] : 0;   // prefetch next index
    unsigned int w = ub[s * 8 + dp];
    a0 += bflo(w); a1 += bfhi(w);
    s = sn;
  }
  if (node < NN) {
    float inv = 1.f / (float)max(cnt, 1);
    unsigned int pk = ((unsigned int)f2bf(a1 * inv) << 16) | f2bf(a0 * inv);
    ((unsigned int*)aggs)[(size_t)slice * NN * 8 + (size_t)node * 8 + dp] = pk;
  }
}

// ---------------- epilogue: h=relu(agg+v+b1); p=h@W2l^T, r=h@W2r^T ---------

__global__ __launch_bounds__(256) void k_post(
    const unsigned short* __restrict__ aggs, const unsigned short* __restrict__ vs,
    const float* __restrict__ b1,
    const float* __restrict__ W2l, const float* __restrict__ W2r,
    unsigned short* __restrict__ p16, float* __restrict__ r) {
  int node = blockIdx.x * 4 + (threadIdx.x >> 6);
  int l = threadIdx.x & 63;
  if (node >= NN) return;
  int sl = l >> 3, dp = l & 7;
  size_t idx = (size_t)sl * NN * 8 + (size_t)node * 8 + dp;
  unsigned int aw = ((const unsigned int*)aggs)[idx];
  unsigned int vw = ((const unsigned int*)vs)[idx];
  int dim = sl * 16 + dp * 2;
  float2 bb = *(const float2*)(b1 + dim);
  float h0 = fmaxf(bflo(aw) + bflo(vw) + bb.x, 0.f);
  float h1 = fmaxf(bfhi(aw) + bfhi(vw) + bb.y, 0.f);

#pragma unroll
  for (int o = 0; o < 8; ++o) {
    const float* wr = (o < 4) ? (W2l + o * 128) : (W2r + (o - 4) * 128);
    float2 wv = *(const float2*)(wr + dim);
    float s = h0 * wv.x + h1 * wv.y;
#pragma unroll
    for (int d = 32; d > 0; d >>= 1) s += __shfl_xor(s, d, 64);
    if (l == o) {
      if (o < 4) p16[(size_t)node * 4 + o] = f2bf(s);
      else       r[(size_t)node * 4 + (o - 4)] = s;
    }
  }
}

// ---------------- layer-2 aggregation (bf16 p, 8B rows) + final linear -----

__global__ void k_final(const unsigned short* __restrict__ p16,
                        const float* __restrict__ r,
                        const int* __restrict__ csr, const int* __restrict__ off,
                        const int* __restrict__ deg,
                        const float* __restrict__ b2,
                        const float* __restrict__ Wlin, const float* __restrict__ blin,
                        float* __restrict__ out) {
  int i = blockIdx.x * blockDim.x + threadIdx.x;
  if (i >= NN) return;
  int cnt = deg[i], st = off[i];
  const uint2* pr = (const uint2*)p16;
  float a0 = 0.f, a1 = 0.f, a2 = 0.f, a3 = 0.f;
  int e = 0;
  for (; e + 4 <= cnt; e += 4) {
    int s0 = csr[st + e], s1 = csr[st + e + 1], s2 = csr[st + e + 2], s3 = csr[st + e + 3];
    uint2 q0 = pr[s0], q1 = pr[s1], q2 = pr[s2], q3 = pr[s3];
    a0 += bflo(q0.x) + bflo(q1.x) + bflo(q2.x) + bflo(q3.x);
    a1 += bfhi(q0.x) + bfhi(q1.x) + bfhi(q2.x) + bfhi(q3.x);
    a2 += bflo(q0.y) + bflo(q1.y) + bflo(q2.y) + bflo(q3.y);
    a3 += bfhi(q0.y) + bfhi(q1.y) + bfhi(q2.y) + bfhi(q3.y);
  }
  for (; e < cnt; ++e) {
    uint2 q = pr[csr[st + e]];
    a0 += bflo(q.x); a1 += bfhi(q.x); a2 += bflo(q.y); a3 += bfhi(q.y);
  }
  float inv = 1.f / (float)max(cnt, 1);
  float4 rv = *(const float4*)(r + (size_t)i * 4);
  float g0 = a0 * inv + b2[0] + rv.x;
  float g1 = a1 * inv + b2[1] + rv.y;
  float g2 = a2 * inv + b2[2] + rv.z;
  float g3 = a3 * inv + b2[3] + rv.w;
  out[(size_t)i * 2 + 0] = g0 * Wlin[0] + g1 * Wlin[1] + g2 * Wlin[2] + g3 * Wlin[3] + blin[0];
  out[(size_t)i * 2 + 1] = g0 * Wlin[4] + g1 * Wlin[5] + g2 * Wlin[6] + g3 * Wlin[7] + blin[1];
}

// ---------------- launch ----------------

extern "C" void kernel_launch(void* const* d_in, const int* in_sizes, int n_in,
                              void* d_out, int out_size, void* d_ws, size_t ws_size,
                              hipStream_t stream) {
  const float* x    = (const float*)d_in[0];
  const int*   ei   = (const int*)d_in[1];
  const int*   src  = ei;
  const int*   dst  = ei + NE;
  const float* W1l  = (const float*)d_in[2];
  const float* b1   = (const float*)d_in[3];
  const float* W1r  = (const float*)d_in[4];
  const float* W2l  = (const float*)d_in[5];
  const float* b2   = (const float*)d_in[6];
  const float* W2r  = (const float*)d_in[7];
  const float* Wlin = (const float*)d_in[8];
  const float* blin = (const float*)d_in[9];
  float* out = (float*)d_out;

  char* w = (char*)d_ws;
  size_t o = 0;
  auto alloc = [&](size_t bytes) {
    void* pp = (void*)(w + o);
    o = (o + bytes + 255) & ~(size_t)255;
    return pp;
  };
  int* hist  = (int*)alloc(NBUK * 4);
  int* bbase = (int*)alloc(NBUK * 4);
  int* gcur  = (int*)alloc(NBUK * 4);
  unsigned int* staged = (unsigned int*)alloc((size_t)NE * 4);
  int* csr   = (int*)alloc((size_t)NE * 4);
  int* offs  = (int*)alloc(NN * 4);
  int* deg   = (int*)alloc(NN * 4);
  unsigned short* Wcat = (unsigned short*)alloc(256 * 128 * 2);
  unsigned short* us   = (unsigned short*)alloc((size_t)NN * 128 * 2);
  unsigned short* vs   = (unsigned short*)alloc((size_t)NN * 128 * 2);
  unsigned short* aggs = (unsigned short*)alloc((size_t)NN * 128 * 2);
  unsigned short* p16  = (unsigned short*)alloc((size_t)NN * 4 * 2);
  float* rbuf = (float*)alloc((size_t)NN * 4 * 4);

  hipLaunchKernelGGL(k_init,  dim3(128), dim3(256), 0, stream, W1l, W1r, Wcat, hist);
  hipLaunchKernelGGL(k_hist,  dim3(NHB), dim3(256), 0, stream, dst, hist);
  hipLaunchKernelGGL(k_scanb, dim3(1), dim3(256), 0, stream, hist, bbase, gcur);
  hipLaunchKernelGGL(k_scatter, dim3((NE + EB - 1) / EB), dim3(256), 0, stream,
                     src, dst, gcur, staged);
  hipLaunchKernelGGL(k_sort2, dim3(NBUK), dim3(256), 0, stream,
                     staged, bbase, hist, csr, offs, deg);
  hipLaunchKernelGGL(k_gemm1, dim3((NN + 63) / 64), dim3(256), 0, stream, x, Wcat, us, vs);
  hipLaunchKernelGGL(k_aggs,  dim3(NAGG * 8), dim3(256), 0, stream,
                     us, csr, offs, deg, aggs);
  hipLaunchKernelGGL(k_post,  dim3(NGRP), dim3(256), 0, stream,
                     aggs, vs, b1, W2l, W2r, p16, rbuf);
  hipLaunchKernelGGL(k_final, dim3((NN + 255) / 256), dim3(256), 0, stream,
                     p16, rbuf, csr, offs, deg, b2, Wlin, blin, out);
}

// Round 8
// 379.548 us; speedup vs baseline: 1.3456x; 1.1857x over previous
//
#include <hip/hip_runtime.h>

#define NN 100000
#define NE 1600000
#define BK 128             // nodes per bucket (scatter/sort)
#define NBUK 782           // ceil(NN/128)
#define EB 8192            // edges per scatter block
#define NHB 98             // ceil(NE/16384) histogram blocks
#define NGRP 25000         // ceil(NN/4) node groups (k_post)

typedef __attribute__((ext_vector_type(8))) short v8s;
typedef __attribute__((ext_vector_type(4))) float v4f;

__device__ __forceinline__ unsigned short f2bf(float f) {
  unsigned int u = __float_as_uint(f);
  unsigned int r = (u + 0x7FFFu + ((u >> 16) & 1u)) >> 16;
  return (unsigned short)r;
}
__device__ __forceinline__ float bflo(unsigned int w) { return __uint_as_float(w << 16); }
__device__ __forceinline__ float bfhi(unsigned int w) { return __uint_as_float(w & 0xFFFF0000u); }

// ---------------- init: pack weights + zero hist ----------------

__global__ void k_init(const float* __restrict__ W1l, const float* __restrict__ W1r,
                       unsigned short* __restrict__ Wcat, int* __restrict__ hist) {
  int i = blockIdx.x * blockDim.x + threadIdx.x;  // 32768 threads
  Wcat[i] = f2bf((i < 16384) ? W1l[i] : W1r[i - 16384]);
  if (i < NBUK) hist[i] = 0;
}

// ---------------- bucket histogram (LDS partial + global atomic) ----------

__global__ __launch_bounds__(256) void k_hist(const int* __restrict__ dst,
                                              int* __restrict__ hist) {
  __shared__ int lh[NBUK];
  int t = threadIdx.x;
  for (int i = t; i < NBUK; i += 256) lh[i] = 0;
  __syncthreads();
  int base = blockIdx.x * 16384;
  int lim = min(16384, NE - base);
  for (int j = t; j < lim; j += 256) atomicAdd(&lh[dst[base + j] >> 7], 1);
  __syncthreads();
  for (int i = t; i < NBUK; i += 256) {
    int c = lh[i];
    if (c) atomicAdd(&hist[i], c);
  }
}

// ---------------- cheap exclusive scan over 782 buckets ----------------

__global__ __launch_bounds__(256) void k_scanb(const int* __restrict__ hist,
                                               int* __restrict__ bbase,
                                               int* __restrict__ gcur) {
  __shared__ int sc[256];
  __shared__ int carry;
  int t = threadIdx.x;
  if (t == 0) carry = 0;
  __syncthreads();
  for (int c = 0; c < (NBUK + 255) / 256; ++c) {
    int i = c * 256 + t;
    int vv = (i < NBUK) ? hist[i] : 0;
    sc[t] = vv;
    __syncthreads();
    for (int o = 1; o < 256; o <<= 1) {
      int uu = (t >= o) ? sc[t - o] : 0;
      __syncthreads();
      sc[t] += uu;
      __syncthreads();
    }
    int excl = carry + sc[t] - vv;
    if (i < NBUK) { bbase[i] = excl; gcur[i] = excl; }
    __syncthreads();
    if (t == 0) carry += sc[255];
    __syncthreads();
  }
}

// ---------------- LDS-staged bucket scatter (linear global writes) ---------

__global__ __launch_bounds__(512) void k_scatter(const int* __restrict__ src,
                                                 const int* __restrict__ dst,
                                                 int* __restrict__ gcur,
                                                 unsigned int* __restrict__ staged) {
  __shared__ unsigned short stageI[EB];                 // 16 KB
  __shared__ int lhist[NBUK], lbase[NBUK], lcur[NBUK], gclaim[NBUK];  // 12.5 KB
  __shared__ int sc[512];
  __shared__ int carry;
  int t = threadIdx.x;
  int e0 = blockIdx.x * EB;
  int ecnt = min(EB, NE - e0);
  for (int i = t; i < NBUK; i += 512) lhist[i] = 0;
  if (t == 0) carry = 0;
  __syncthreads();
  for (int j = t; j < ecnt; j += 512) atomicAdd(&lhist[dst[e0 + j] >> 7], 1);
  __syncthreads();
  for (int c = 0; c < (NBUK + 511) / 512; ++c) {
    int i = c * 512 + t;
    int vv = (i < NBUK) ? lhist[i] : 0;
    sc[t] = vv;
    __syncthreads();
    for (int o = 1; o < 512; o <<= 1) {
      int uu = (t >= o) ? sc[t - o] : 0;
      __syncthreads();
      sc[t] += uu;
      __syncthreads();
    }
    int excl = carry + sc[t] - vv;
    if (i < NBUK) { lbase[i] = excl; lcur[i] = excl; }
    __syncthreads();
    if (t == 0) carry += sc[511];
    __syncthreads();
  }
  for (int b = t; b < NBUK; b += 512) {
    int c = lhist[b];
    gclaim[b] = c ? atomicAdd(&gcur[b], c) : 0;
  }
  __syncthreads();
  for (int j = t; j < ecnt; j += 512) {
    int b = dst[e0 + j] >> 7;
    int lp = atomicAdd(&lcur[b], 1);
    stageI[lp] = (unsigned short)j;
  }
  __syncthreads();
  for (int i = t; i < ecnt; i += 512) {
    int j = stageI[i];
    int d = dst[e0 + j];
    int b = d >> 7;
    staged[gclaim[b] + (i - lbase[b])] =
        ((unsigned int)src[e0 + j] << 7) | (unsigned int)(d & 127);
  }
}

// ---------------- per-bucket radix pass 2: staged -> CSR + off + deg -------

__global__ __launch_bounds__(256) void k_sort2(const unsigned int* __restrict__ staged,
                                               const int* __restrict__ bbase,
                                               const int* __restrict__ hist,
                                               int* __restrict__ csr,
                                               int* __restrict__ off,
                                               int* __restrict__ deg) {
  __shared__ int h128[BK], c128[BK];
  __shared__ int wtot;
  int bkt = blockIdx.x, t = threadIdx.x;
  if (t < BK) h128[t] = 0;
  __syncthreads();
  int st = bbase[bkt], cnt = hist[bkt];
  for (int j = t; j < cnt; j += 256) atomicAdd(&h128[staged[st + j] & 127], 1);
  __syncthreads();
  int v = 0, inc = 0;
  if (t < BK) {
    v = h128[t];
    inc = v;
    for (int o = 1; o < 64; o <<= 1) {
      int uu = __shfl_up(inc, o, 64);
      if ((t & 63) >= o) inc += uu;
    }
    if (t == 63) wtot = inc;
  }
  __syncthreads();
  if (t < BK) {
    int excl = inc - v + ((t >= 64) ? wtot : 0);
    c128[t] = excl;
    int node = bkt * BK + t;
    if (node < NN) { off[node] = st + excl; deg[node] = v; }
  }
  __syncthreads();
  for (int j = t; j < cnt; j += 256) {
    unsigned pk = staged[st + j];
    int lp = atomicAdd(&c128[pk & 127], 1);
    csr[st + lp] = (int)(pk >> 7);
  }
}

// ---------------- MFMA GEMM: us = x@W1l^T, vs = x@W1r^T ----------
// outputs in slice-major layout [slice][node][16] bf16

__global__ __launch_bounds__(256) void k_gemm1(
    const float* __restrict__ x, const unsigned short* __restrict__ Wcat,
    unsigned short* __restrict__ us, unsigned short* __restrict__ vs) {
  int wave = threadIdx.x >> 6, l = threadIdx.x & 63;
  int m0 = blockIdx.x * 64 + wave * 16;
  if (m0 >= NN) return;
  int lr = l & 15, kq = l >> 4;
  int rowc = min(m0 + lr, NN - 1);

  v8s a[4];
#pragma unroll
  for (int ks = 0; ks < 4; ++ks) {
    const float* xp = x + (size_t)rowc * 128 + ks * 32 + kq * 8;
    float4 f0 = *(const float4*)xp;
    float4 f1 = *(const float4*)(xp + 4);
    v8s tv;
    tv[0] = (short)f2bf(f0.x); tv[1] = (short)f2bf(f0.y);
    tv[2] = (short)f2bf(f0.z); tv[3] = (short)f2bf(f0.w);
    tv[4] = (short)f2bf(f1.x); tv[5] = (short)f2bf(f1.y);
    tv[6] = (short)f2bf(f1.z); tv[7] = (short)f2bf(f1.w);
    a[ks] = tv;
  }

  v4f acc[16];
#pragma unroll
  for (int nt = 0; nt < 16; ++nt) acc[nt] = (v4f){0.f, 0.f, 0.f, 0.f};

#pragma unroll
  for (int nt = 0; nt < 16; ++nt) {
    const unsigned short* wrow = Wcat + (size_t)(nt * 16 + lr) * 128;
#pragma unroll
    for (int ks = 0; ks < 4; ++ks) {
      v8s b = *(const v8s*)(wrow + ks * 32 + kq * 8);
      acc[nt] = __builtin_amdgcn_mfma_f32_16x16x32_bf16(a[ks], b, acc[nt], 0, 0, 0);
    }
  }

#pragma unroll
  for (int nt = 0; nt < 16; ++nt) {
#pragma unroll
    for (int rr = 0; rr < 4; ++rr) {
      int mrow = m0 + kq * 4 + rr;
      if (mrow < NN) {
        unsigned short bv = f2bf(acc[nt][rr]);
        if (nt < 8) us[(size_t)nt * NN * 16 + (size_t)mrow * 16 + lr] = bv;
        else        vs[(size_t)(nt - 8) * NN * 16 + (size_t)mrow * 16 + lr] = bv;
      }
    }
  }
}

// ---------------- sliced mean-agg + relu fuse (XCD-L2-resident gather) -----
// wave = 16 nodes x 4 lanes; lane gathers uint2 (4 dims) per edge, 4-edge
// unroll -> 4 independent gathers in flight. slice = blockIdx & 7 pins the
// 3.2 MB slice working set to one XCD's L2. Writes h = relu(agg+v+b1).

__global__ __launch_bounds__(256) void k_aggs(
    const unsigned short* __restrict__ us, const unsigned short* __restrict__ vs,
    const float* __restrict__ b1,
    const int* __restrict__ csr, const int* __restrict__ off,
    const int* __restrict__ deg,
    unsigned short* __restrict__ hs) {
  int slice = blockIdx.x & 7;
  int grp = blockIdx.x >> 3;               // 64 nodes per block (4 waves x 16)
  int t = threadIdx.x;
  int wave = t >> 6, l = t & 63;
  int g = l >> 2, dp = l & 3;              // 16 node-groups x 4 lanes
  int node = grp * 64 + wave * 16 + g;
  const uint2* ub = (const uint2*)us + (size_t)slice * NN * 4;

  int cnt = 0, st = 0;
  if (node < NN) { cnt = deg[node]; st = off[node]; }

  float a0 = 0.f, a1 = 0.f, a2 = 0.f, a3 = 0.f;
  for (int e = 0; e < cnt; e += 4) {
    int c0 = csr[st + min(e + 0, cnt - 1)];
    int c1 = csr[st + min(e + 1, cnt - 1)];
    int c2 = csr[st + min(e + 2, cnt - 1)];
    int c3 = csr[st + min(e + 3, cnt - 1)];
    uint2 w0 = ub[(size_t)c0 * 4 + dp];
    uint2 w1 = ub[(size_t)c1 * 4 + dp];
    uint2 w2 = ub[(size_t)c2 * 4 + dp];
    uint2 w3 = ub[(size_t)c3 * 4 + dp];
    float m1 = (e + 1 < cnt) ? 1.f : 0.f;
    float m2 = (e + 2 < cnt) ? 1.f : 0.f;
    float m3 = (e + 3 < cnt) ? 1.f : 0.f;
    a0 += bflo(w0.x);            a1 += bfhi(w0.x);
    a2 += bflo(w0.y);            a3 += bfhi(w0.y);
    a0 = fmaf(m1, bflo(w1.x), a0); a1 = fmaf(m1, bfhi(w1.x), a1);
    a2 = fmaf(m1, bflo(w1.y), a2); a3 = fmaf(m1, bfhi(w1.y), a3);
    a0 = fmaf(m2, bflo(w2.x), a0); a1 = fmaf(m2, bfhi(w2.x), a1);
    a2 = fmaf(m2, bflo(w2.y), a2); a3 = fmaf(m2, bfhi(w2.y), a3);
    a0 = fmaf(m3, bflo(w3.x), a0); a1 = fmaf(m3, bfhi(w3.x), a1);
    a2 = fmaf(m3, bflo(w3.y), a2); a3 = fmaf(m3, bfhi(w3.y), a3);
  }
  if (node < NN) {
    float inv = 1.f / (float)max(cnt, 1);
    size_t idx = ((size_t)slice * NN + node) * 4 + dp;
    uint2 vw = ((const uint2*)vs)[idx];
    float4 bb = *(const float4*)(b1 + slice * 16 + dp * 4);
    float h0 = fmaxf(fmaf(a0, inv, bflo(vw.x) + bb.x), 0.f);
    float h1 = fmaxf(fmaf(a1, inv, bfhi(vw.x) + bb.y), 0.f);
    float h2 = fmaxf(fmaf(a2, inv, bflo(vw.y) + bb.z), 0.f);
    float h3 = fmaxf(fmaf(a3, inv, bfhi(vw.y) + bb.w), 0.f);
    uint2 pk;
    pk.x = ((unsigned int)f2bf(h1) << 16) | f2bf(h0);
    pk.y = ((unsigned int)f2bf(h3) << 16) | f2bf(h2);
    ((uint2*)hs)[idx] = pk;
  }
}

// ---------------- projection: p = h@W2l^T, r = h@W2r^T ---------------------

__global__ __launch_bounds__(256) void k_post(
    const unsigned short* __restrict__ hs,
    const float* __restrict__ W2l, const float* __restrict__ W2r,
    unsigned short* __restrict__ p16, float* __restrict__ r) {
  int node = blockIdx.x * 4 + (threadIdx.x >> 6);
  int l = threadIdx.x & 63;
  if (node >= NN) return;
  int sl = l >> 3, dp = l & 7;
  unsigned int hw = ((const unsigned int*)hs)[((size_t)sl * NN + node) * 8 + dp];
  int dim = sl * 16 + dp * 2;
  float h0 = bflo(hw), h1 = bfhi(hw);

#pragma unroll
  for (int o = 0; o < 8; ++o) {
    const float* wr = (o < 4) ? (W2l + o * 128) : (W2r + (o - 4) * 128);
    float2 wv = *(const float2*)(wr + dim);
    float s = h0 * wv.x + h1 * wv.y;
#pragma unroll
    for (int d = 32; d > 0; d >>= 1) s += __shfl_xor(s, d, 64);
    if (l == o) {
      if (o < 4) p16[(size_t)node * 4 + o] = f2bf(s);
      else       r[(size_t)node * 4 + (o - 4)] = s;
    }
  }
}

// ---------------- layer-2 aggregation (bf16 p, 8B rows) + final linear -----

__global__ void k_final(const unsigned short* __restrict__ p16,
                        const float* __restrict__ r,
                        const int* __restrict__ csr, const int* __restrict__ off,
                        const int* __restrict__ deg,
                        const float* __restrict__ b2,
                        const float* __restrict__ Wlin, const float* __restrict__ blin,
                        float* __restrict__ out) {
  int i = blockIdx.x * blockDim.x + threadIdx.x;
  if (i >= NN) return;
  int cnt = deg[i], st = off[i];
  const uint2* pr = (const uint2*)p16;
  float a0 = 0.f, a1 = 0.f, a2 = 0.f, a3 = 0.f;
  int e = 0;
  for (; e + 4 <= cnt; e += 4) {
    int s0 = csr[st + e], s1 = csr[st + e + 1], s2 = csr[st + e + 2], s3 = csr[st + e + 3];
    uint2 q0 = pr[s0], q1 = pr[s1], q2 = pr[s2], q3 = pr[s3];
    a0 += bflo(q0.x) + bflo(q1.x) + bflo(q2.x) + bflo(q3.x);
    a1 += bfhi(q0.x) + bfhi(q1.x) + bfhi(q2.x) + bfhi(q3.x);
    a2 += bflo(q0.y) + bflo(q1.y) + bflo(q2.y) + bflo(q3.y);
    a3 += bfhi(q0.y) + bfhi(q1.y) + bfhi(q2.y) + bfhi(q3.y);
  }
  for (; e < cnt; ++e) {
    uint2 q = pr[csr[st + e]];
    a0 += bflo(q.x); a1 += bfhi(q.x); a2 += bflo(q.y); a3 += bfhi(q.y);
  }
  float inv = 1.f / (float)max(cnt, 1);
  float4 rv = *(const float4*)(r + (size_t)i * 4);
  float g0 = a0 * inv + b2[0] + rv.x;
  float g1 = a1 * inv + b2[1] + rv.y;
  float g2 = a2 * inv + b2[2] + rv.z;
  float g3 = a3 * inv + b2[3] + rv.w;
  out[(size_t)i * 2 + 0] = g0 * Wlin[0] + g1 * Wlin[1] + g2 * Wlin[2] + g3 * Wlin[3] + blin[0];
  out[(size_t)i * 2 + 1] = g0 * Wlin[4] + g1 * Wlin[5] + g2 * Wlin[6] + g3 * Wlin[7] + blin[1];
}

// ---------------- launch ----------------

extern "C" void kernel_launch(void* const* d_in, const int* in_sizes, int n_in,
                              void* d_out, int out_size, void* d_ws, size_t ws_size,
                              hipStream_t stream) {
  const float* x    = (const float*)d_in[0];
  const int*   ei   = (const int*)d_in[1];
  const int*   src  = ei;
  const int*   dst  = ei + NE;
  const float* W1l  = (const float*)d_in[2];
  const float* b1   = (const float*)d_in[3];
  const float* W1r  = (const float*)d_in[4];
  const float* W2l  = (const float*)d_in[5];
  const float* b2   = (const float*)d_in[6];
  const float* W2r  = (const float*)d_in[7];
  const float* Wlin = (const float*)d_in[8];
  const float* blin = (const float*)d_in[9];
  float* out = (float*)d_out;

  char* w = (char*)d_ws;
  size_t o = 0;
  auto alloc = [&](size_t bytes) {
    void* pp = (void*)(w + o);
    o = (o + bytes + 255) & ~(size_t)255;
    return pp;
  };
  int* hist  = (int*)alloc(NBUK * 4);
  int* bbase = (int*)alloc(NBUK * 4);
  int* gcur  = (int*)alloc(NBUK * 4);
  unsigned int* staged = (unsigned int*)alloc((size_t)NE * 4);
  int* csr   = (int*)alloc((size_t)NE * 4);
  int* offs  = (int*)alloc(NN * 4);
  int* deg   = (int*)alloc(NN * 4);
  unsigned short* Wcat = (unsigned short*)alloc(256 * 128 * 2);
  unsigned short* us   = (unsigned short*)alloc((size_t)NN * 128 * 2);
  unsigned short* vs   = (unsigned short*)alloc((size_t)NN * 128 * 2);
  unsigned short* hs   = (unsigned short*)alloc((size_t)NN * 128 * 2);
  unsigned short* p16  = (unsigned short*)alloc((size_t)NN * 4 * 2);
  float* rbuf = (float*)alloc((size_t)NN * 4 * 4);

  hipLaunchKernelGGL(k_init,  dim3(128), dim3(256), 0, stream, W1l, W1r, Wcat, hist);
  hipLaunchKernelGGL(k_hist,  dim3(NHB), dim3(256), 0, stream, dst, hist);
  hipLaunchKernelGGL(k_scanb, dim3(1), dim3(256), 0, stream, hist, bbase, gcur);
  hipLaunchKernelGGL(k_scatter, dim3((NE + EB - 1) / EB), dim3(512), 0, stream,
                     src, dst, gcur, staged);
  hipLaunchKernelGGL(k_sort2, dim3(NBUK), dim3(256), 0, stream,
                     staged, bbase, hist, csr, offs, deg);
  hipLaunchKernelGGL(k_gemm1, dim3((NN + 63) / 64), dim3(256), 0, stream, x, Wcat, us, vs);
  hipLaunchKernelGGL(k_aggs,  dim3(1563 * 8), dim3(256), 0, stream,
                     us, vs, b1, csr, offs, deg, hs);
  hipLaunchKernelGGL(k_post,  dim3(NGRP), dim3(256), 0, stream,
                     hs, W2l, W2r, p16, rbuf);
  hipLaunchKernelGGL(k_final, dim3((NN + 255) / 256), dim3(256), 0, stream,
                     p16, rbuf, csr, offs, deg, b2, Wlin, blin, out);
}